// Round 16
// baseline (295.365 us; speedup 1.0000x reference)
//
#include <hip/hip_runtime.h>
#include <math.h>

#define Bb 4
#define Ss 512
#define Hh 768
#define Vv 30522
#define Aa 200

typedef float f32x4 __attribute__((ext_vector_type(4)));
typedef short short8 __attribute__((ext_vector_type(8)));
typedef short short4v __attribute__((ext_vector_type(4)));
typedef __bf16 bf16x8 __attribute__((ext_vector_type(8)));

__device__ __forceinline__ unsigned short f2bf(float f) {
  union { float f; unsigned u; } v; v.f = f;
  unsigned r = v.u + 0x7FFFu + ((v.u >> 16) & 1u);
  return (unsigned short)(r >> 16);
}

__device__ __forceinline__ void gload16(const void* g, void* l) {
  __builtin_amdgcn_global_load_lds(
      (const __attribute__((address_space(1))) void*)g,
      (__attribute__((address_space(3))) void*)l, 16, 0, 0);
}

#define BAR()   do { asm volatile("" ::: "memory"); __builtin_amdgcn_s_barrier(); asm volatile("" ::: "memory"); } while(0)
#define VMW(n)  asm volatile("s_waitcnt vmcnt(" #n ")" ::: "memory")

// ---------------- fused_pre: wconv(Wout) + wconv(Wfc) + k1 in one launch ---
// Deterministic, no inter-wave sync outside the k1 branch (branch is
// block-uniform). Validated in r15's first pass.
#define K1_TOK 8
__global__ __launch_bounds__(256) void fused_pre(
    const float* __restrict__ hidden, const float* __restrict__ W1,
    const float* __restrict__ b1, const float* __restrict__ v_attn,
    float* __restrict__ s_buf,
    const float* __restrict__ Wfc, unsigned short* __restrict__ wfcb,
    const float* __restrict__ Wout, unsigned short* __restrict__ woutb)
{
  __shared__ float hsm[K1_TOK][Hh];
  __shared__ float part[K1_TOK][4];
  const int bid = blockIdx.x;
  const int tid = threadIdx.x;
  if (bid < 2048) {                       // wconv W_out
    const int n4 = Vv * Hh / 4;
    for (int i = bid * 256 + tid; i < n4; i += 2048 * 256) {
      f32x4 v = *reinterpret_cast<const f32x4*>(Wout + (size_t)i * 4);
      short4v p;
      #pragma unroll
      for (int q = 0; q < 4; ++q) p[q] = (short)f2bf(v[q]);
      *reinterpret_cast<short4v*>(woutb + (size_t)i * 4) = p;
    }
    return;
  }
  if (bid < 2304) {                       // wconv W_fc
    const int n4 = Hh * Hh / 4;
    for (int i = (bid - 2048) * 256 + tid; i < n4; i += 256 * 256) {
      f32x4 v = *reinterpret_cast<const f32x4*>(Wfc + (size_t)i * 4);
      short4v p;
      #pragma unroll
      for (int q = 0; q < 4; ++q) p[q] = (short)f2bf(v[q]);
      *reinterpret_cast<short4v*>(wfcb + (size_t)i * 4) = p;
    }
    return;
  }
  // k1: s[tok] = sum_a v_a * tanh(W1[a,:].h[tok] + b1[a])
  const int tok0 = (bid - 2304) * K1_TOK;
  #pragma unroll
  for (int i = 0; i < (K1_TOK * Hh / 4) / 256; ++i) {
    int c = i * 256 + tid;
    int row = c / (Hh / 4);
    int col4 = c % (Hh / 4);
    f32x4 v = *reinterpret_cast<const f32x4*>(hidden + (size_t)(tok0 + row) * Hh + col4 * 4);
    *reinterpret_cast<f32x4*>(&hsm[row][col4 * 4]) = v;
  }
  __syncthreads();
  float acc[K1_TOK];
  #pragma unroll
  for (int t = 0; t < K1_TOK; ++t) acc[t] = 0.f;
  if (tid < Aa) {
    const float* wr = W1 + (size_t)tid * Hh;
    for (int h = 0; h < Hh; h += 4) {
      f32x4 w4 = *reinterpret_cast<const f32x4*>(wr + h);
      #pragma unroll
      for (int t = 0; t < K1_TOK; ++t) {
        f32x4 h4 = *reinterpret_cast<const f32x4*>(&hsm[t][h]);
        acc[t] += w4[0]*h4[0] + w4[1]*h4[1] + w4[2]*h4[2] + w4[3]*h4[3];
      }
    }
  }
  const int lane = tid & 63, wv = tid >> 6;
  #pragma unroll
  for (int t = 0; t < K1_TOK; ++t) {
    float x = (tid < Aa) ? v_attn[tid] * tanhf(acc[t] + b1[tid]) : 0.f;
    #pragma unroll
    for (int o = 32; o > 0; o >>= 1) x += __shfl_xor(x, o);
    if (lane == 0) part[t][wv] = x;
  }
  __syncthreads();
  if (tid < K1_TOK)
    s_buf[tok0 + tid] = part[tid][0] + part[tid][1] + part[tid][2] + part[tid][3];
}

// ---------------- K1.5: per-batch e = exp(s-max), prefix + suffix sums -----
#define ZLD 520
__global__ __launch_bounds__(256) void k15_pre(
    const float* __restrict__ s_buf, float* __restrict__ e_buf,
    float* __restrict__ zpref, float* __restrict__ zsuf)
{
  const int b = blockIdx.x, tid = threadIdx.x;
  __shared__ float se[512];
  __shared__ float bA[512], bB[512];
  __shared__ float pm[4];
  float v0 = s_buf[b * 512 + tid], v1 = s_buf[b * 512 + 256 + tid];
  float m = fmaxf(v0, v1);
  #pragma unroll
  for (int o = 32; o > 0; o >>= 1) m = fmaxf(m, __shfl_xor(m, o));
  if ((tid & 63) == 0) pm[tid >> 6] = m;
  __syncthreads();
  float M = fmaxf(fmaxf(pm[0], pm[1]), fmaxf(pm[2], pm[3]));
  float e0 = expf(v0 - M), e1 = expf(v1 - M);
  se[tid] = e0; se[tid + 256] = e1;
  e_buf[b * 512 + tid] = e0; e_buf[b * 512 + 256 + tid] = e1;
  bA[tid] = e0; bA[tid + 256] = e1;
  __syncthreads();
  float* src = bA; float* dst = bB;
  for (int off = 1; off < 512; off <<= 1) {
    for (int i = tid; i < 512; i += 256)
      dst[i] = src[i] + ((i >= off) ? src[i - off] : 0.f);
    __syncthreads();
    float* t = src; src = dst; dst = t;
  }
  if (tid == 0) zpref[b * ZLD] = 0.f;
  zpref[b * ZLD + 1 + tid] = src[tid];
  zpref[b * ZLD + 257 + tid] = src[tid + 256];
  __syncthreads();
  src[tid] = se[tid]; src[tid + 256] = se[tid + 256];
  __syncthreads();
  for (int off = 1; off < 512; off <<= 1) {
    for (int i = tid; i < 512; i += 256)
      dst[i] = src[i] + ((i + off < 512) ? src[i + off] : 0.f);
    __syncthreads();
    float* t = src; src = dst; dst = t;
  }
  zsuf[b * ZLD + tid] = src[tid];
  zsuf[b * ZLD + 256 + tid] = src[tid + 256];
  if (tid == 0) zsuf[b * ZLD + 512] = 0.f;
}

// ---------------- K2a: per-16-chunk partial sums of e_k * h[k][f] ----------
__global__ __launch_bounds__(256) void k2a_part(
    const float* __restrict__ hidden, const float* __restrict__ e_buf,
    float* __restrict__ spart)
{
  const int bid = blockIdx.x;
  const int fc = bid % 3, c = (bid / 3) % 32, b = bid / 96;
  const int f = fc * 256 + threadIdx.x;
  float acc = 0.f;
  #pragma unroll 4
  for (int kk = 0; kk < 16; ++kk) {
    int k = c * 16 + kk;
    acc += e_buf[b * 512 + k] * hidden[((size_t)(b * 512 + k)) * Hh + f];
  }
  spart[((size_t)b * 32 + c) * Hh + f] = acc;
}

// ---------------- K2c: scan -> hidd (fp32 to d_out, bf16 to ws) ------------
__global__ __launch_bounds__(256) void k2c_scan(
    const float* __restrict__ hidden, const float* __restrict__ e_buf,
    const float* __restrict__ zpref, const float* __restrict__ zsuf,
    const float* __restrict__ spart, const int* __restrict__ ptype,
    float* __restrict__ out_hidd, unsigned short* __restrict__ hbf)
{
  const int bid = blockIdx.x;
  const int fc = bid % 3, q = (bid / 3) % 16, b = bid / 48;
  const int f = fc * 256 + threadIdx.x;
  const int type = ptype[b];
  const float* Sp = spart + (size_t)b * 32 * Hh;
  const float* Zp = zpref + b * ZLD;
  const float* Zs = zsuf + b * ZLD;
  const size_t hbase = (size_t)b * 512 * Hh + f;
  const int j0 = q * 32;
  if (type == 0) {
    float run = 0.f;
    for (int c = 0; c < q * 2; ++c) run += Sp[c * Hh + f];
    for (int jj = 0; jj < 32; ++jj) {
      int j = j0 + jj;
      float ev = e_buf[b * 512 + j];
      float h = hidden[hbase + (size_t)j * Hh];
      run += ev * h;
      float val = run / (Zp[j + 1] * (float)(j + 1));
      out_hidd[hbase + (size_t)j * Hh] = val;
      hbf[hbase + (size_t)j * Hh] = f2bf(val);
    }
  } else if (type == 1) {
    float run = 0.f;
    for (int c = q * 2 + 2; c < 32; ++c) run += Sp[c * Hh + f];
    for (int jj = 31; jj >= 0; --jj) {
      int j = j0 + jj;
      float ev = e_buf[b * 512 + j];
      float h = hidden[hbase + (size_t)j * Hh];
      run += ev * h;
      float val = run / (Zs[j] * (float)(512 - j));
      out_hidd[hbase + (size_t)j * Hh] = val;
      hbf[hbase + (size_t)j * Hh] = f2bf(val);
    }
  } else {
    float T = 0.f;
    for (int c = 0; c < 32; ++c) T += Sp[c * Hh + f];
    float Ztot = Zp[512];
    for (int jj = 0; jj < 32; ++jj) {
      int j = j0 + jj;
      float ev = e_buf[b * 512 + j];
      float h = hidden[hbase + (size_t)j * Hh];
      float val = (T - ev * h) / ((Ztot - ev) * 511.0f);
      out_hidd[hbase + (size_t)j * Hh] = val;
      hbf[hbase + (size_t)j * Hh] = f2bf(val);
    }
  }
}

// ---------------- gemm4 (r11-exact): 128x128 4-wave BK=32, triple buffer ---
// Single barrier per K-step; VGPR=68 (no spill -> counted VMW sound).
// Passed r11 & r12-era validation; vocab GEMM 143 us.
#define CPAD 132
__global__ __launch_bounds__(256, 3) void gemm4(
    const unsigned short* __restrict__ Abf, const unsigned short* __restrict__ Bbf,
    const float* __restrict__ bias, float* __restrict__ C,
    const int M, const int N, const int K, const int ntm)
{
  __shared__ __attribute__((aligned(16))) unsigned char lds[49152];
  const int tid = threadIdx.x;
  const int total = gridDim.x;
  int bid = blockIdx.x;
  if ((total & 7) == 0) bid = (bid & 7) * (total >> 3) + (bid >> 3);  // XCD-chunked
  const int bm = bid % ntm;
  const int bn = bid / ntm;
  const int lane = tid & 63;
  const int wv = tid >> 6;
  const int wr = wv >> 1;
  const int wc = wv & 1;
  const int r15 = lane & 15, kg = lane >> 4;
  const int nt = K / 32;

  unsigned offA[2], offB[2];
  int ldsg[2];
  #pragma unroll
  for (int i = 0; i < 2; ++i) {
    int g = i * 256 + tid;
    int r = ((g >> 6) << 4) | ((g >> 2) & 15);
    int c = (g & 3) ^ ((g >> 4) & 3);
    offA[i] = (unsigned)((bm * 128 + r) * K + c * 8);
    int rb = bn * 128 + r; if (rb >= N) rb = N - 1;
    offB[i] = (unsigned)(rb * K + c * 8);
    ldsg[i] = g * 16;
  }
  const int xq = (kg ^ ((r15 >> 2) & 3)) << 4;

#define STG(t, d) do { \
    unsigned char* lb_ = lds + (d) * 16384; \
    gload16(Abf + offA[0] + (t) * 32, lb_ + ldsg[0]); \
    gload16(Abf + offA[1] + (t) * 32, lb_ + ldsg[1]); \
    gload16(Bbf + offB[0] + (t) * 32, lb_ + 8192 + ldsg[0]); \
    gload16(Bbf + offB[1] + (t) * 32, lb_ + 8192 + ldsg[1]); \
  } while (0)
#define RDALL(d) do { \
    const unsigned char* ab_ = lds + (d) * 16384 + wr * 4096 + r15 * 64 + xq; \
    const unsigned char* bb_ = lds + (d) * 16384 + 8192 + wc * 4096 + r15 * 64 + xq; \
    af[0]  = *reinterpret_cast<const bf16x8*>(ab_); \
    bfr[0] = *reinterpret_cast<const bf16x8*>(bb_); \
    af[1]  = *reinterpret_cast<const bf16x8*>(ab_ + 1024); \
    bfr[1] = *reinterpret_cast<const bf16x8*>(bb_ + 1024); \
    af[2]  = *reinterpret_cast<const bf16x8*>(ab_ + 2048); \
    bfr[2] = *reinterpret_cast<const bf16x8*>(bb_ + 2048); \
    af[3]  = *reinterpret_cast<const bf16x8*>(ab_ + 3072); \
    bfr[3] = *reinterpret_cast<const bf16x8*>(bb_ + 3072); \
  } while (0)

  f32x4 acc[4][4];
  #pragma unroll
  for (int m = 0; m < 4; ++m)
    #pragma unroll
    for (int n = 0; n < 4; ++n)
      #pragma unroll
      for (int r = 0; r < 4; ++r) acc[m][n][r] = 0.f;
  bf16x8 af[4], bfr[4];

  STG(0, 0);
  STG(1, 1);
  VMW(4);
  BAR();

  int c0 = 0, c2 = 2;
  for (int t = 0; t < nt; ++t) {
    RDALL(c0);
    if (t + 2 < nt) STG(t + 2, c2);
    __builtin_amdgcn_s_setprio(1);
    #pragma unroll
    for (int mm = 0; mm < 4; ++mm)
      #pragma unroll
      for (int nn = 0; nn < 4; ++nn)
        acc[mm][nn] = __builtin_amdgcn_mfma_f32_16x16x32_bf16(af[mm], bfr[nn], acc[mm][nn], 0, 0, 0);
    __builtin_amdgcn_s_setprio(0);
    if (t + 2 < nt) { VMW(4); } else { VMW(0); }
    BAR();
    c0 = (c0 == 2) ? 0 : c0 + 1;
    c2 = (c2 == 2) ? 0 : c2 + 1;
  }

  // ---- epilogue: LDS-staged (padded stride), NT full-line stores ----
  float* ldsf = (float*)lds;
  int nvt = N - bn * 128; if (nvt > 128) nvt = 128;
  const int nv = nvt;
  const int colc = (tid & 31) * 4;
  const int rsub = tid >> 5;
  #pragma unroll
  for (int half = 0; half < 2; ++half) {
    BAR();
    if (wr == half) {
      #pragma unroll
      for (int n = 0; n < 4; ++n) {
        int colg = bn * 128 + wc * 64 + n * 16 + r15;
        float bv = (colg < N) ? bias[colg] : 0.f;
        int cloc = wc * 64 + n * 16 + r15;
        #pragma unroll
        for (int m = 0; m < 4; ++m) {
          int rloc = m * 16 + kg * 4;
          #pragma unroll
          for (int rr = 0; rr < 4; ++rr)
            ldsf[(rloc + rr) * CPAD + cloc] = acc[m][n][rr] + bv;
        }
      }
    }
    BAR();
    const int rbase0 = bm * 128 + half * 64;
    if (colc < nv) {
      if (colc + 3 < nv) {
        #pragma unroll
        for (int qq = 0; qq < 8; ++qq) {
          int row = qq * 8 + rsub;
          f32x4 v = *reinterpret_cast<const f32x4*>(&ldsf[row * CPAD + colc]);
          __builtin_nontemporal_store(v,
              reinterpret_cast<f32x4*>(&C[(size_t)(rbase0 + row) * N + bn * 128 + colc]));
        }
      } else {
        for (int qq = 0; qq < 8; ++qq) {
          int row = qq * 8 + rsub;
          f32x4 v = *reinterpret_cast<const f32x4*>(&ldsf[row * CPAD + colc]);
          size_t ga = (size_t)(rbase0 + row) * N + bn * 128 + colc;
          #pragma unroll
          for (int e = 0; e < 4; ++e)
            if (colc + e < nv) C[ga + e] = v[e];
        }
      }
    }
  }
#undef STG
#undef RDALL
}

// ---------------- fallback GEMM (fp32 B, on-the-fly convert) ---------------
#define GBM 128
#define GBN 128
#define GBK 64
__global__ __launch_bounds__(256) void gemm_bt(
    const unsigned short* __restrict__ Abf, const float* __restrict__ Bsrc,
    const float* __restrict__ bias, float* __restrict__ C,
    const int M, const int N, const int K, const int ntm)
{
  __shared__ unsigned short As[GBM * GBK];
  __shared__ unsigned short Bs[GBN * GBK];
  const int tid = threadIdx.x;
  const int total = gridDim.x;
  int bid = blockIdx.x;
  if ((total & 7) == 0) bid = (bid & 7) * (total >> 3) + (bid >> 3);
  const int bm = bid % ntm;
  const int bn = bid / ntm;
  const int lane = tid & 63;
  const int wv = tid >> 6;
  const int wr = wv >> 1, wc = wv & 1;
  const int r15 = lane & 15, kg = lane >> 4;

  f32x4 acc[4][4];
  #pragma unroll
  for (int m = 0; m < 4; ++m)
    #pragma unroll
    for (int n = 0; n < 4; ++n)
      #pragma unroll
      for (int r = 0; r < 4; ++r) acc[m][n][r] = 0.f;

  for (int kt = 0; kt < K; kt += GBK) {
    __syncthreads();
    #pragma unroll
    for (int i = 0; i < 4; ++i) {
      int c = i * 256 + tid;
      int row = c >> 3, col8 = c & 7;
      short8 v = *reinterpret_cast<const short8*>(Abf + (size_t)(bm * GBM + row) * K + kt + col8 * 8);
      int idx = (row * GBK + col8 * 8) ^ ((row & 7) << 3);
      *reinterpret_cast<short8*>(&As[idx]) = v;
    }
    #pragma unroll
    for (int i = 0; i < 8; ++i) {
      int c = i * 256 + tid;
      int row = c >> 4, col4 = c & 15;
      int nsrc = bn * GBN + row; nsrc = nsrc < N ? nsrc : N - 1;
      f32x4 v = *reinterpret_cast<const f32x4*>(Bsrc + (size_t)nsrc * K + kt + col4 * 4);
      short4v p;
      #pragma unroll
      for (int q = 0; q < 4; ++q) p[q] = (short)f2bf(v[q]);
      int idx = (row * GBK + col4 * 4) ^ ((row & 7) << 3);
      *reinterpret_cast<short4v*>(&Bs[idx]) = p;
    }
    __syncthreads();
    #pragma unroll
    for (int kk = 0; kk < GBK / 32; ++kk) {
      bf16x8 af[4], bf[4];
      #pragma unroll
      for (int m = 0; m < 4; ++m) {
        int row = wr * 64 + m * 16 + r15;
        int col = kk * 32 + kg * 8;
        af[m] = *reinterpret_cast<const bf16x8*>(&As[(row * GBK + col) ^ ((row & 7) << 3)]);
      }
      #pragma unroll
      for (int n = 0; n < 4; ++n) {
        int row = wc * 64 + n * 16 + r15;
        int col = kk * 32 + kg * 8;
        bf[n] = *reinterpret_cast<const bf16x8*>(&Bs[(row * GBK + col) ^ ((row & 7) << 3)]);
      }
      #pragma unroll
      for (int m = 0; m < 4; ++m)
        #pragma unroll
        for (int n = 0; n < 4; ++n)
          acc[m][n] = __builtin_amdgcn_mfma_f32_16x16x32_bf16(af[m], bf[n], acc[m][n], 0, 0, 0);
    }
  }
  #pragma unroll
  for (int n = 0; n < 4; ++n) {
    int col = bn * GBN + wc * 64 + n * 16 + r15;
    if (col < N) {
      float bv = bias[col];
      #pragma unroll
      for (int m = 0; m < 4; ++m) {
        int rbase = bm * GBM + wr * 64 + m * 16 + kg * 4;
        #pragma unroll
        for (int r = 0; r < 4; ++r)
          C[(size_t)(rbase + r) * N + col] = acc[m][n][r] + bv;
      }
    }
  }
}

// ---------------- K3b: exact GELU + LayerNorm -> xn (bf16) -----------------
__global__ __launch_bounds__(256) void k3b_geluln(
    const float* __restrict__ x, const float* __restrict__ gam,
    const float* __restrict__ bet, unsigned short* __restrict__ xnbf)
{
  const int row = blockIdx.x, tid = threadIdx.x;
  __shared__ float part[4];
  float g[3];
  float s = 0.f;
  #pragma unroll
  for (int i = 0; i < 3; ++i) {
    float xv = x[(size_t)row * Hh + tid + 256 * i];
    float t = 0.5f * xv * (1.f + erff(xv * 0.70710678118654752f));
    g[i] = t; s += t;
  }
  #pragma unroll
  for (int o = 32; o > 0; o >>= 1) s += __shfl_xor(s, o);
  if ((tid & 63) == 0) part[tid >> 6] = s;
  __syncthreads();
  float mu = (part[0] + part[1] + part[2] + part[3]) * (1.f / 768.f);
  __syncthreads();
  float vs = 0.f;
  #pragma unroll
  for (int i = 0; i < 3; ++i) { float d = g[i] - mu; vs += d * d; }
  #pragma unroll
  for (int o = 32; o > 0; o >>= 1) vs += __shfl_xor(vs, o);
  if ((tid & 63) == 0) part[tid >> 6] = vs;
  __syncthreads();
  float var = (part[0] + part[1] + part[2] + part[3]) * (1.f / 768.f);
  float inv = 1.0f / sqrtf(var + 1e-12f);
  #pragma unroll
  for (int i = 0; i < 3; ++i) {
    int f = tid + 256 * i;
    xnbf[(size_t)row * Hh + f] = f2bf((g[i] - mu) * inv * gam[f] + bet[f]);
  }
}

extern "C" void kernel_launch(void* const* d_in, const int* in_sizes, int n_in,
                              void* d_out, int out_size, void* d_ws, size_t ws_size,
                              hipStream_t stream)
{
  const float* hidden = (const float*)d_in[0];
  const int*   ptype  = (const int*)d_in[1];
  const float* W1     = (const float*)d_in[2];
  const float* b1     = (const float*)d_in[3];
  const float* vat    = (const float*)d_in[4];
  const float* Wfc    = (const float*)d_in[5];
  const float* bfc    = (const float*)d_in[6];
  const float* lng    = (const float*)d_in[7];
  const float* lnb    = (const float*)d_in[8];
  const float* Wout   = (const float*)d_in[9];
  const float* bout   = (const float*)d_in[10];

  float* out_hidd = (float*)d_out;
  float* out_logits = out_hidd + (size_t)Bb * Ss * Hh;

  // workspace layout (float offsets); xnbf reuses hbf (dead after FC GEMM)
  float* ws = (float*)d_ws;
  float* s_buf = ws;                                   // [0, 2048)
  float* e_buf = ws + 2048;                            // [2048, 4096)
  float* zpref = ws + 4096;                            // [4096, 6176)
  float* zsuf  = ws + 6176;                            // [6176, 8256)
  float* xbuf  = ws + 8256;                            // [8256, 1581120)
  float* spart = ws + 1581120;                         // [1581120, 1679424)
  unsigned short* hbf  = (unsigned short*)(ws + 1679424);   // 2048*768 bf16
  unsigned short* xnbf = hbf;                               // reuse (hbf dead)
  unsigned short* wfcb = (unsigned short*)(ws + 2465856);   // 768*768 bf16
  unsigned short* woutb = (unsigned short*)(ws + 2760768);  // 30522*768 bf16
  const size_t need = (size_t)2760768 * 4 + (size_t)Vv * Hh * 2;  // ~57.9 MB

  const bool pre = ws_size >= need;

  if (pre) {
    fused_pre<<<dim3(2304 + Bb * Ss / K1_TOK), dim3(256), 0, stream>>>(
        hidden, W1, b1, vat, s_buf, Wfc, wfcb, Wout, woutb);
  } else {
    fused_pre<<<dim3(2304 + Bb * Ss / K1_TOK), dim3(256), 0, stream>>>(
        hidden, W1, b1, vat, s_buf, Wfc, wfcb, Wout, woutb);
  }
  k15_pre<<<dim3(Bb), dim3(256), 0, stream>>>(s_buf, e_buf, zpref, zsuf);
  k2a_part<<<dim3(Bb * 32 * 3), dim3(256), 0, stream>>>(hidden, e_buf, spart);
  k2c_scan<<<dim3(Bb * 16 * 3), dim3(256), 0, stream>>>(hidden, e_buf, zpref, zsuf,
                                                        spart, ptype, out_hidd, hbf);
  if (pre) {
    gemm4<<<dim3((2048 / 128) * (Hh / 128)), dim3(256), 0, stream>>>(
        hbf, wfcb, bfc, xbuf, 2048, Hh, Hh, 2048 / 128);
  } else {
    gemm_bt<<<dim3((2048 / GBM) * (Hh / GBN)), dim3(256), 0, stream>>>(
        hbf, Wfc, bfc, xbuf, 2048, Hh, Hh, 2048 / GBM);
  }
  k3b_geluln<<<dim3(2048), dim3(256), 0, stream>>>(xbuf, lng, lnb, xnbf);
  if (pre) {
    gemm4<<<dim3((2048 / 128) * ((Vv + 127) / 128)), dim3(256), 0, stream>>>(
        xnbf, woutb, bout, out_logits, 2048, Vv, Hh, 2048 / 128);
  } else {
    gemm_bt<<<dim3((2048 / GBM) * ((Vv + GBN - 1) / GBN)), dim3(256), 0, stream>>>(
        xnbf, Wout, bout, out_logits, 2048, Vv, Hh, 2048 / GBM);
  }
}

// Round 17
// 265.671 us; speedup vs baseline: 1.1118x; 1.1118x over previous
//
#include <hip/hip_runtime.h>
#include <math.h>

#define Bb 4
#define Ss 512
#define Hh 768
#define Vv 30522
#define Aa 200

typedef float f32x4 __attribute__((ext_vector_type(4)));
typedef short short8 __attribute__((ext_vector_type(8)));
typedef short short4v __attribute__((ext_vector_type(4)));
typedef __bf16 bf16x8 __attribute__((ext_vector_type(8)));

__device__ __forceinline__ unsigned short f2bf(float f) {
  union { float f; unsigned u; } v; v.f = f;
  unsigned r = v.u + 0x7FFFu + ((v.u >> 16) & 1u);
  return (unsigned short)(r >> 16);
}

__device__ __forceinline__ void gload16(const void* g, void* l) {
  __builtin_amdgcn_global_load_lds(
      (const __attribute__((address_space(1))) void*)g,
      (__attribute__((address_space(3))) void*)l, 16, 0, 0);
}

#define BAR()   do { asm volatile("" ::: "memory"); __builtin_amdgcn_s_barrier(); asm volatile("" ::: "memory"); } while(0)
#define VMW(n)  asm volatile("s_waitcnt vmcnt(" #n ")" ::: "memory")

// ---------------- K0: fp32 -> bf16 weight conversion -----------------------
__global__ __launch_bounds__(256) void wconv(
    const float* __restrict__ src, unsigned short* __restrict__ dst, int n4)
{
  int i = blockIdx.x * 256 + threadIdx.x;
  const int stride = gridDim.x * 256;
  for (; i < n4; i += stride) {
    f32x4 v = *reinterpret_cast<const f32x4*>(src + (size_t)i * 4);
    short4v p;
    #pragma unroll
    for (int q = 0; q < 4; ++q) p[q] = (short)f2bf(v[q]);
    *reinterpret_cast<short4v*>(dst + (size_t)i * 4) = p;
  }
}

// ---------------- w1t: transpose W1 [200][768] -> W1T [768][200] -----------
__global__ __launch_bounds__(256) void w1t_k(
    const float* __restrict__ W1, float* __restrict__ W1T)
{
  int i = blockIdx.x * 256 + threadIdx.x;
  if (i < Aa * Hh) {
    int a = i / Hh, h = i - a * Hh;
    W1T[h * Aa + a] = W1[i];
  }
}

// ---------------- K1: s[tok] = sum_a v_a * tanh(W1[a,:].h[tok] + b1[a]) ----
// W1 accessed via transposed copy W1T[h][a]: lane=a -> coalesced loads
// (200 x 4B contiguous per h). Accumulation order per token identical to the
// r1-r15 kernel (w0*h0+w1*h1+w2*h2+w3*h3 per 4-wide h step).
#define K1_TOK 8
__global__ __launch_bounds__(256) void k1_score(
    const float* __restrict__ hidden, const float* __restrict__ W1T,
    const float* __restrict__ b1, const float* __restrict__ v_attn,
    float* __restrict__ s_buf)
{
  __shared__ float hsm[K1_TOK][Hh];
  __shared__ float part[K1_TOK][4];
  const int tid = threadIdx.x;
  const int tok0 = blockIdx.x * K1_TOK;
  #pragma unroll
  for (int i = 0; i < (K1_TOK * Hh / 4) / 256; ++i) {   // 6 iters
    int c = i * 256 + tid;
    int row = c / (Hh / 4);
    int col4 = c % (Hh / 4);
    f32x4 v = *reinterpret_cast<const f32x4*>(hidden + (size_t)(tok0 + row) * Hh + col4 * 4);
    *reinterpret_cast<f32x4*>(&hsm[row][col4 * 4]) = v;
  }
  __syncthreads();
  float acc[K1_TOK];
  #pragma unroll
  for (int t = 0; t < K1_TOK; ++t) acc[t] = 0.f;
  if (tid < Aa) {
    for (int h = 0; h < Hh; h += 4) {
      float w0 = W1T[(h + 0) * Aa + tid];
      float w1 = W1T[(h + 1) * Aa + tid];
      float w2 = W1T[(h + 2) * Aa + tid];
      float w3 = W1T[(h + 3) * Aa + tid];
      #pragma unroll
      for (int t = 0; t < K1_TOK; ++t) {
        acc[t] += w0 * hsm[t][h] + w1 * hsm[t][h + 1]
                + w2 * hsm[t][h + 2] + w3 * hsm[t][h + 3];
      }
    }
  }
  const int lane = tid & 63, wv = tid >> 6;
  #pragma unroll
  for (int t = 0; t < K1_TOK; ++t) {
    float x = (tid < Aa) ? v_attn[tid] * tanhf(acc[t] + b1[tid]) : 0.f;
    #pragma unroll
    for (int o = 32; o > 0; o >>= 1) x += __shfl_xor(x, o);
    if (lane == 0) part[t][wv] = x;
  }
  __syncthreads();
  if (tid < K1_TOK)
    s_buf[tok0 + tid] = part[tid][0] + part[tid][1] + part[tid][2] + part[tid][3];
}

// ---------------- K1.5: per-batch e = exp(s-max), prefix + suffix sums -----
#define ZLD 520
__global__ __launch_bounds__(256) void k15_pre(
    const float* __restrict__ s_buf, float* __restrict__ e_buf,
    float* __restrict__ zpref, float* __restrict__ zsuf)
{
  const int b = blockIdx.x, tid = threadIdx.x;
  __shared__ float se[512];
  __shared__ float bA[512], bB[512];
  __shared__ float pm[4];
  float v0 = s_buf[b * 512 + tid], v1 = s_buf[b * 512 + 256 + tid];
  float m = fmaxf(v0, v1);
  #pragma unroll
  for (int o = 32; o > 0; o >>= 1) m = fmaxf(m, __shfl_xor(m, o));
  if ((tid & 63) == 0) pm[tid >> 6] = m;
  __syncthreads();
  float M = fmaxf(fmaxf(pm[0], pm[1]), fmaxf(pm[2], pm[3]));
  float e0 = expf(v0 - M), e1 = expf(v1 - M);
  se[tid] = e0; se[tid + 256] = e1;
  e_buf[b * 512 + tid] = e0; e_buf[b * 512 + 256 + tid] = e1;
  bA[tid] = e0; bA[tid + 256] = e1;
  __syncthreads();
  float* src = bA; float* dst = bB;
  for (int off = 1; off < 512; off <<= 1) {
    for (int i = tid; i < 512; i += 256)
      dst[i] = src[i] + ((i >= off) ? src[i - off] : 0.f);
    __syncthreads();
    float* t = src; src = dst; dst = t;
  }
  if (tid == 0) zpref[b * ZLD] = 0.f;
  zpref[b * ZLD + 1 + tid] = src[tid];
  zpref[b * ZLD + 257 + tid] = src[tid + 256];
  __syncthreads();
  src[tid] = se[tid]; src[tid + 256] = se[tid + 256];
  __syncthreads();
  for (int off = 1; off < 512; off <<= 1) {
    for (int i = tid; i < 512; i += 256)
      dst[i] = src[i] + ((i + off < 512) ? src[i + off] : 0.f);
    __syncthreads();
    float* t = src; src = dst; dst = t;
  }
  zsuf[b * ZLD + tid] = src[tid];
  zsuf[b * ZLD + 256 + tid] = src[tid + 256];
  if (tid == 0) zsuf[b * ZLD + 512] = 0.f;
}

// ---------------- K2a: per-16-chunk partial sums of e_k * h[k][f] ----------
__global__ __launch_bounds__(256) void k2a_part(
    const float* __restrict__ hidden, const float* __restrict__ e_buf,
    float* __restrict__ spart)
{
  const int bid = blockIdx.x;
  const int fc = bid % 3, c = (bid / 3) % 32, b = bid / 96;
  const int f = fc * 256 + threadIdx.x;
  float acc = 0.f;
  #pragma unroll 4
  for (int kk = 0; kk < 16; ++kk) {
    int k = c * 16 + kk;
    acc += e_buf[b * 512 + k] * hidden[((size_t)(b * 512 + k)) * Hh + f];
  }
  spart[((size_t)b * 32 + c) * Hh + f] = acc;
}

// ---------------- K2c: scan -> hidd (fp32 to d_out, bf16 to ws) ------------
__global__ __launch_bounds__(256) void k2c_scan(
    const float* __restrict__ hidden, const float* __restrict__ e_buf,
    const float* __restrict__ zpref, const float* __restrict__ zsuf,
    const float* __restrict__ spart, const int* __restrict__ ptype,
    float* __restrict__ out_hidd, unsigned short* __restrict__ hbf)
{
  const int bid = blockIdx.x;
  const int fc = bid % 3, q = (bid / 3) % 16, b = bid / 48;
  const int f = fc * 256 + threadIdx.x;
  const int type = ptype[b];
  const float* Sp = spart + (size_t)b * 32 * Hh;
  const float* Zp = zpref + b * ZLD;
  const float* Zs = zsuf + b * ZLD;
  const size_t hbase = (size_t)b * 512 * Hh + f;
  const int j0 = q * 32;
  if (type == 0) {
    float run = 0.f;
    for (int c = 0; c < q * 2; ++c) run += Sp[c * Hh + f];
    for (int jj = 0; jj < 32; ++jj) {
      int j = j0 + jj;
      float ev = e_buf[b * 512 + j];
      float h = hidden[hbase + (size_t)j * Hh];
      run += ev * h;
      float val = run / (Zp[j + 1] * (float)(j + 1));
      out_hidd[hbase + (size_t)j * Hh] = val;
      hbf[hbase + (size_t)j * Hh] = f2bf(val);
    }
  } else if (type == 1) {
    float run = 0.f;
    for (int c = q * 2 + 2; c < 32; ++c) run += Sp[c * Hh + f];
    for (int jj = 31; jj >= 0; --jj) {
      int j = j0 + jj;
      float ev = e_buf[b * 512 + j];
      float h = hidden[hbase + (size_t)j * Hh];
      run += ev * h;
      float val = run / (Zs[j] * (float)(512 - j));
      out_hidd[hbase + (size_t)j * Hh] = val;
      hbf[hbase + (size_t)j * Hh] = f2bf(val);
    }
  } else {
    float T = 0.f;
    for (int c = 0; c < 32; ++c) T += Sp[c * Hh + f];
    float Ztot = Zp[512];
    for (int jj = 0; jj < 32; ++jj) {
      int j = j0 + jj;
      float ev = e_buf[b * 512 + j];
      float h = hidden[hbase + (size_t)j * Hh];
      float val = (T - ev * h) / ((Ztot - ev) * 511.0f);
      out_hidd[hbase + (size_t)j * Hh] = val;
      hbf[hbase + (size_t)j * Hh] = f2bf(val);
    }
  }
}

// ---------------- gemm4 (r11-exact): 128x128 4-wave BK=32, triple buffer ---
// Single barrier per K-step; VGPR=68 (no spill -> counted VMW sound).
// Measured r11: vocab GEMM 143 us, passed.
#define CPAD 132
__global__ __launch_bounds__(256, 3) void gemm4(
    const unsigned short* __restrict__ Abf, const unsigned short* __restrict__ Bbf,
    const float* __restrict__ bias, float* __restrict__ C,
    const int M, const int N, const int K, const int ntm)
{
  __shared__ __attribute__((aligned(16))) unsigned char lds[49152];
  const int tid = threadIdx.x;
  const int total = gridDim.x;
  int bid = blockIdx.x;
  if ((total & 7) == 0) bid = (bid & 7) * (total >> 3) + (bid >> 3);  // XCD-chunked
  const int bm = bid % ntm;
  const int bn = bid / ntm;
  const int lane = tid & 63;
  const int wv = tid >> 6;
  const int wr = wv >> 1;
  const int wc = wv & 1;
  const int r15 = lane & 15, kg = lane >> 4;
  const int nt = K / 32;

  unsigned offA[2], offB[2];
  int ldsg[2];
  #pragma unroll
  for (int i = 0; i < 2; ++i) {
    int g = i * 256 + tid;
    int r = ((g >> 6) << 4) | ((g >> 2) & 15);
    int c = (g & 3) ^ ((g >> 4) & 3);
    offA[i] = (unsigned)((bm * 128 + r) * K + c * 8);
    int rb = bn * 128 + r; if (rb >= N) rb = N - 1;
    offB[i] = (unsigned)(rb * K + c * 8);
    ldsg[i] = g * 16;
  }
  const int xq = (kg ^ ((r15 >> 2) & 3)) << 4;

#define STG(t, d) do { \
    unsigned char* lb_ = lds + (d) * 16384; \
    gload16(Abf + offA[0] + (t) * 32, lb_ + ldsg[0]); \
    gload16(Abf + offA[1] + (t) * 32, lb_ + ldsg[1]); \
    gload16(Bbf + offB[0] + (t) * 32, lb_ + 8192 + ldsg[0]); \
    gload16(Bbf + offB[1] + (t) * 32, lb_ + 8192 + ldsg[1]); \
  } while (0)
#define RDALL(d) do { \
    const unsigned char* ab_ = lds + (d) * 16384 + wr * 4096 + r15 * 64 + xq; \
    const unsigned char* bb_ = lds + (d) * 16384 + 8192 + wc * 4096 + r15 * 64 + xq; \
    af[0]  = *reinterpret_cast<const bf16x8*>(ab_); \
    bfr[0] = *reinterpret_cast<const bf16x8*>(bb_); \
    af[1]  = *reinterpret_cast<const bf16x8*>(ab_ + 1024); \
    bfr[1] = *reinterpret_cast<const bf16x8*>(bb_ + 1024); \
    af[2]  = *reinterpret_cast<const bf16x8*>(ab_ + 2048); \
    bfr[2] = *reinterpret_cast<const bf16x8*>(bb_ + 2048); \
    af[3]  = *reinterpret_cast<const bf16x8*>(ab_ + 3072); \
    bfr[3] = *reinterpret_cast<const bf16x8*>(bb_ + 3072); \
  } while (0)

  f32x4 acc[4][4];
  #pragma unroll
  for (int m = 0; m < 4; ++m)
    #pragma unroll
    for (int n = 0; n < 4; ++n)
      #pragma unroll
      for (int r = 0; r < 4; ++r) acc[m][n][r] = 0.f;
  bf16x8 af[4], bfr[4];

  STG(0, 0);
  STG(1, 1);
  VMW(4);
  BAR();

  int c0 = 0, c2 = 2;
  for (int t = 0; t < nt; ++t) {
    RDALL(c0);
    if (t + 2 < nt) STG(t + 2, c2);
    __builtin_amdgcn_s_setprio(1);
    #pragma unroll
    for (int mm = 0; mm < 4; ++mm)
      #pragma unroll
      for (int nn = 0; nn < 4; ++nn)
        acc[mm][nn] = __builtin_amdgcn_mfma_f32_16x16x32_bf16(af[mm], bfr[nn], acc[mm][nn], 0, 0, 0);
    __builtin_amdgcn_s_setprio(0);
    if (t + 2 < nt) { VMW(4); } else { VMW(0); }
    BAR();
    c0 = (c0 == 2) ? 0 : c0 + 1;
    c2 = (c2 == 2) ? 0 : c2 + 1;
  }

  // ---- epilogue: LDS-staged (padded stride), NT full-line stores ----
  float* ldsf = (float*)lds;
  int nvt = N - bn * 128; if (nvt > 128) nvt = 128;
  const int nv = nvt;
  const int colc = (tid & 31) * 4;
  const int rsub = tid >> 5;
  #pragma unroll
  for (int half = 0; half < 2; ++half) {
    BAR();
    if (wr == half) {
      #pragma unroll
      for (int n = 0; n < 4; ++n) {
        int colg = bn * 128 + wc * 64 + n * 16 + r15;
        float bv = (colg < N) ? bias[colg] : 0.f;
        int cloc = wc * 64 + n * 16 + r15;
        #pragma unroll
        for (int m = 0; m < 4; ++m) {
          int rloc = m * 16 + kg * 4;
          #pragma unroll
          for (int rr = 0; rr < 4; ++rr)
            ldsf[(rloc + rr) * CPAD + cloc] = acc[m][n][rr] + bv;
        }
      }
    }
    BAR();
    const int rbase0 = bm * 128 + half * 64;
    if (colc < nv) {
      if (colc + 3 < nv) {
        #pragma unroll
        for (int qq = 0; qq < 8; ++qq) {
          int row = qq * 8 + rsub;
          f32x4 v = *reinterpret_cast<const f32x4*>(&ldsf[row * CPAD + colc]);
          __builtin_nontemporal_store(v,
              reinterpret_cast<f32x4*>(&C[(size_t)(rbase0 + row) * N + bn * 128 + colc]));
        }
      } else {
        for (int qq = 0; qq < 8; ++qq) {
          int row = qq * 8 + rsub;
          f32x4 v = *reinterpret_cast<const f32x4*>(&ldsf[row * CPAD + colc]);
          size_t ga = (size_t)(rbase0 + row) * N + bn * 128 + colc;
          #pragma unroll
          for (int e = 0; e < 4; ++e)
            if (colc + e < nv) C[ga + e] = v[e];
        }
      }
    }
  }
#undef STG
#undef RDALL
}

// ---------------- fallback GEMM (fp32 B, on-the-fly convert) ---------------
#define GBM 128
#define GBN 128
#define GBK 64
__global__ __launch_bounds__(256) void gemm_bt(
    const unsigned short* __restrict__ Abf, const float* __restrict__ Bsrc,
    const float* __restrict__ bias, float* __restrict__ C,
    const int M, const int N, const int K, const int ntm)
{
  __shared__ unsigned short As[GBM * GBK];
  __shared__ unsigned short Bs[GBN * GBK];
  const int tid = threadIdx.x;
  const int total = gridDim.x;
  int bid = blockIdx.x;
  if ((total & 7) == 0) bid = (bid & 7) * (total >> 3) + (bid >> 3);
  const int bm = bid % ntm;
  const int bn = bid / ntm;
  const int lane = tid & 63;
  const int wv = tid >> 6;
  const int wr = wv >> 1, wc = wv & 1;
  const int r15 = lane & 15, kg = lane >> 4;

  f32x4 acc[4][4];
  #pragma unroll
  for (int m = 0; m < 4; ++m)
    #pragma unroll
    for (int n = 0; n < 4; ++n)
      #pragma unroll
      for (int r = 0; r < 4; ++r) acc[m][n][r] = 0.f;

  for (int kt = 0; kt < K; kt += GBK) {
    __syncthreads();
    #pragma unroll
    for (int i = 0; i < 4; ++i) {
      int c = i * 256 + tid;
      int row = c >> 3, col8 = c & 7;
      short8 v = *reinterpret_cast<const short8*>(Abf + (size_t)(bm * GBM + row) * K + kt + col8 * 8);
      int idx = (row * GBK + col8 * 8) ^ ((row & 7) << 3);
      *reinterpret_cast<short8*>(&As[idx]) = v;
    }
    #pragma unroll
    for (int i = 0; i < 8; ++i) {
      int c = i * 256 + tid;
      int row = c >> 4, col4 = c & 15;
      int nsrc = bn * GBN + row; nsrc = nsrc < N ? nsrc : N - 1;
      f32x4 v = *reinterpret_cast<const f32x4*>(Bsrc + (size_t)nsrc * K + kt + col4 * 4);
      short4v p;
      #pragma unroll
      for (int q = 0; q < 4; ++q) p[q] = (short)f2bf(v[q]);
      int idx = (row * GBK + col4 * 4) ^ ((row & 7) << 3);
      *reinterpret_cast<short4v*>(&Bs[idx]) = p;
    }
    __syncthreads();
    #pragma unroll
    for (int kk = 0; kk < GBK / 32; ++kk) {
      bf16x8 af[4], bf[4];
      #pragma unroll
      for (int m = 0; m < 4; ++m) {
        int row = wr * 64 + m * 16 + r15;
        int col = kk * 32 + kg * 8;
        af[m] = *reinterpret_cast<const bf16x8*>(&As[(row * GBK + col) ^ ((row & 7) << 3)]);
      }
      #pragma unroll
      for (int n = 0; n < 4; ++n) {
        int row = wc * 64 + n * 16 + r15;
        int col = kk * 32 + kg * 8;
        bf[n] = *reinterpret_cast<const bf16x8*>(&Bs[(row * GBK + col) ^ ((row & 7) << 3)]);
      }
      #pragma unroll
      for (int m = 0; m < 4; ++m)
        #pragma unroll
        for (int n = 0; n < 4; ++n)
          acc[m][n] = __builtin_amdgcn_mfma_f32_16x16x32_bf16(af[m], bf[n], acc[m][n], 0, 0, 0);
    }
  }
  #pragma unroll
  for (int n = 0; n < 4; ++n) {
    int col = bn * GBN + wc * 64 + n * 16 + r15;
    if (col < N) {
      float bv = bias[col];
      #pragma unroll
      for (int m = 0; m < 4; ++m) {
        int rbase = bm * GBM + wr * 64 + m * 16 + kg * 4;
        #pragma unroll
        for (int r = 0; r < 4; ++r)
          C[(size_t)(rbase + r) * N + col] = acc[m][n][r] + bv;
      }
    }
  }
}

// ---------------- K3b: exact GELU + LayerNorm -> xn (bf16) -----------------
__global__ __launch_bounds__(256) void k3b_geluln(
    const float* __restrict__ x, const float* __restrict__ gam,
    const float* __restrict__ bet, unsigned short* __restrict__ xnbf)
{
  const int row = blockIdx.x, tid = threadIdx.x;
  __shared__ float part[4];
  float g[3];
  float s = 0.f;
  #pragma unroll
  for (int i = 0; i < 3; ++i) {
    float xv = x[(size_t)row * Hh + tid + 256 * i];
    float t = 0.5f * xv * (1.f + erff(xv * 0.70710678118654752f));
    g[i] = t; s += t;
  }
  #pragma unroll
  for (int o = 32; o > 0; o >>= 1) s += __shfl_xor(s, o);
  if ((tid & 63) == 0) part[tid >> 6] = s;
  __syncthreads();
  float mu = (part[0] + part[1] + part[2] + part[3]) * (1.f / 768.f);
  __syncthreads();
  float vs = 0.f;
  #pragma unroll
  for (int i = 0; i < 3; ++i) { float d = g[i] - mu; vs += d * d; }
  #pragma unroll
  for (int o = 32; o > 0; o >>= 1) vs += __shfl_xor(vs, o);
  if ((tid & 63) == 0) part[tid >> 6] = vs;
  __syncthreads();
  float var = (part[0] + part[1] + part[2] + part[3]) * (1.f / 768.f);
  float inv = 1.0f / sqrtf(var + 1e-12f);
  #pragma unroll
  for (int i = 0; i < 3; ++i) {
    int f = tid + 256 * i;
    xnbf[(size_t)row * Hh + f] = f2bf((g[i] - mu) * inv * gam[f] + bet[f]);
  }
}

extern "C" void kernel_launch(void* const* d_in, const int* in_sizes, int n_in,
                              void* d_out, int out_size, void* d_ws, size_t ws_size,
                              hipStream_t stream)
{
  const float* hidden = (const float*)d_in[0];
  const int*   ptype  = (const int*)d_in[1];
  const float* W1     = (const float*)d_in[2];
  const float* b1     = (const float*)d_in[3];
  const float* vat    = (const float*)d_in[4];
  const float* Wfc    = (const float*)d_in[5];
  const float* bfc    = (const float*)d_in[6];
  const float* lng    = (const float*)d_in[7];
  const float* lnb    = (const float*)d_in[8];
  const float* Wout   = (const float*)d_in[9];
  const float* bout   = (const float*)d_in[10];

  float* out_hidd = (float*)d_out;
  float* out_logits = out_hidd + (size_t)Bb * Ss * Hh;

  // workspace layout (float offsets); xnbf reuses hbf (dead after FC GEMM)
  float* ws = (float*)d_ws;
  float* s_buf = ws;                                   // [0, 2048)
  float* e_buf = ws + 2048;                            // [2048, 4096)
  float* zpref = ws + 4096;                            // [4096, 6176)
  float* zsuf  = ws + 6176;                            // [6176, 8256)
  float* xbuf  = ws + 8256;                            // [8256, 1581120)
  float* spart = ws + 1581120;                         // [1581120, 1679424)
  unsigned short* hbf  = (unsigned short*)(ws + 1679424);   // 2048*768 bf16
  unsigned short* xnbf = hbf;                               // reuse (hbf dead)
  unsigned short* wfcb = (unsigned short*)(ws + 2465856);   // 768*768 bf16
  unsigned short* woutb = (unsigned short*)(ws + 2760768);  // 30522*768 bf16
  float* w1tb = ws + 2760768 + (Vv * Hh / 2);               // 768*200 fp32
  const size_t need = ((size_t)2760768 + (size_t)Vv * Hh / 2 + Aa * Hh) * 4;  // ~58.5 MB

  const bool pre = ws_size >= need;

  w1t_k<<<dim3((Aa * Hh + 255) / 256), dim3(256), 0, stream>>>(W1, pre ? w1tb : (float*)d_ws);
  k1_score<<<dim3(Bb * Ss / K1_TOK), dim3(256), 0, stream>>>(
      hidden, pre ? w1tb : (float*)d_ws, b1, vat, s_buf);
  k15_pre<<<dim3(Bb), dim3(256), 0, stream>>>(s_buf, e_buf, zpref, zsuf);
  if (pre) {
    wconv<<<dim3(256), dim3(256), 0, stream>>>(Wfc, wfcb, Hh * Hh / 4);
    wconv<<<dim3(2048), dim3(256), 0, stream>>>(Wout, woutb, Vv * Hh / 4);
  }
  k2a_part<<<dim3(Bb * 32 * 3), dim3(256), 0, stream>>>(hidden, e_buf, spart);
  k2c_scan<<<dim3(Bb * 16 * 3), dim3(256), 0, stream>>>(hidden, e_buf, zpref, zsuf,
                                                        spart, ptype, out_hidd, hbf);
  if (pre) {
    gemm4<<<dim3((2048 / 128) * (Hh / 128)), dim3(256), 0, stream>>>(
        hbf, wfcb, bfc, xbuf, 2048, Hh, Hh, 2048 / 128);
  } else {
    gemm_bt<<<dim3((2048 / GBM) * (Hh / GBN)), dim3(256), 0, stream>>>(
        hbf, Wfc, bfc, xbuf, 2048, Hh, Hh, 2048 / GBM);
  }
  k3b_geluln<<<dim3(2048), dim3(256), 0, stream>>>(xbuf, lng, lnb, xnbf);
  if (pre) {
    gemm4<<<dim3((2048 / 128) * ((Vv + 127) / 128)), dim3(256), 0, stream>>>(
        xnbf, woutb, bout, out_logits, 2048, Vv, Hh, 2048 / 128);
  } else {
    gemm_bt<<<dim3((2048 / GBM) * ((Vv + GBN - 1) / GBN)), dim3(256), 0, stream>>>(
        xnbf, Wout, bout, out_logits, 2048, Vv, Hh, 2048 / GBM);
  }
}

// Round 18
// 254.273 us; speedup vs baseline: 1.1616x; 1.0448x over previous
//
#include <hip/hip_runtime.h>
#include <math.h>

#define Bb 4
#define Ss 512
#define Hh 768
#define Vv 30522
#define Aa 200

typedef float f32x4 __attribute__((ext_vector_type(4)));
typedef short short8 __attribute__((ext_vector_type(8)));
typedef short short4v __attribute__((ext_vector_type(4)));
typedef __bf16 bf16x8 __attribute__((ext_vector_type(8)));

__device__ __forceinline__ unsigned short f2bf(float f) {
  union { float f; unsigned u; } v; v.f = f;
  unsigned r = v.u + 0x7FFFu + ((v.u >> 16) & 1u);
  return (unsigned short)(r >> 16);
}

__device__ __forceinline__ void gload16(const void* g, void* l) {
  __builtin_amdgcn_global_load_lds(
      (const __attribute__((address_space(1))) void*)g,
      (__attribute__((address_space(3))) void*)l, 16, 0, 0);
}

#define BAR()   do { asm volatile("" ::: "memory"); __builtin_amdgcn_s_barrier(); asm volatile("" ::: "memory"); } while(0)
#define VMW(n)  asm volatile("s_waitcnt vmcnt(" #n ")" ::: "memory")

// ---------------- wconv2: both weight conversions in one launch ------------
// Pure streaming, block-uniform branch, no LDS/sync: deterministic.
// (These are exactly the r16 fused_pre wconv branches, which were correct.)
__global__ __launch_bounds__(256) void wconv2(
    const float* __restrict__ Wout, unsigned short* __restrict__ woutb,
    const float* __restrict__ Wfc, unsigned short* __restrict__ wfcb)
{
  const int bid = blockIdx.x;
  const int tid = threadIdx.x;
  if (bid < 2048) {                       // W_out: 94MB read + 47MB write
    const int n4 = Vv * Hh / 4;
    for (int i = bid * 256 + tid; i < n4; i += 2048 * 256) {
      f32x4 v = *reinterpret_cast<const f32x4*>(Wout + (size_t)i * 4);
      short4v p;
      #pragma unroll
      for (int q = 0; q < 4; ++q) p[q] = (short)f2bf(v[q]);
      *reinterpret_cast<short4v*>(woutb + (size_t)i * 4) = p;
    }
  } else {                                // W_fc
    const int n4 = Hh * Hh / 4;
    for (int i = (bid - 2048) * 256 + tid; i < n4; i += 256 * 256) {
      f32x4 v = *reinterpret_cast<const f32x4*>(Wfc + (size_t)i * 4);
      short4v p;
      #pragma unroll
      for (int q = 0; q < 4; ++q) p[q] = (short)f2bf(v[q]);
      *reinterpret_cast<short4v*>(wfcb + (size_t)i * 4) = p;
    }
  }
}

// ---------------- K1: s[tok] = sum_a v_a * tanh(W1[a,:].h[tok] + b1[a]) ----
// (r11-exact: W1 row layout; each lane reads a contiguous f32x4 of its row;
// W1 = 614KB -> L2-resident at this occupancy.)
#define K1_TOK 8
__global__ __launch_bounds__(256) void k1_score(
    const float* __restrict__ hidden, const float* __restrict__ W1,
    const float* __restrict__ b1, const float* __restrict__ v_attn,
    float* __restrict__ s_buf)
{
  __shared__ float hsm[K1_TOK][Hh];
  __shared__ float part[K1_TOK][4];
  const int tid = threadIdx.x;
  const int tok0 = blockIdx.x * K1_TOK;
  #pragma unroll
  for (int i = 0; i < (K1_TOK * Hh / 4) / 256; ++i) {   // 6 iters
    int c = i * 256 + tid;
    int row = c / (Hh / 4);
    int col4 = c % (Hh / 4);
    f32x4 v = *reinterpret_cast<const f32x4*>(hidden + (size_t)(tok0 + row) * Hh + col4 * 4);
    *reinterpret_cast<f32x4*>(&hsm[row][col4 * 4]) = v;
  }
  __syncthreads();
  float acc[K1_TOK];
  #pragma unroll
  for (int t = 0; t < K1_TOK; ++t) acc[t] = 0.f;
  if (tid < Aa) {
    const float* wr = W1 + (size_t)tid * Hh;
    for (int h = 0; h < Hh; h += 4) {
      f32x4 w4 = *reinterpret_cast<const f32x4*>(wr + h);
      #pragma unroll
      for (int t = 0; t < K1_TOK; ++t) {
        f32x4 h4 = *reinterpret_cast<const f32x4*>(&hsm[t][h]);
        acc[t] += w4[0]*h4[0] + w4[1]*h4[1] + w4[2]*h4[2] + w4[3]*h4[3];
      }
    }
  }
  const int lane = tid & 63, wv = tid >> 6;
  #pragma unroll
  for (int t = 0; t < K1_TOK; ++t) {
    float x = (tid < Aa) ? v_attn[tid] * tanhf(acc[t] + b1[tid]) : 0.f;
    #pragma unroll
    for (int o = 32; o > 0; o >>= 1) x += __shfl_xor(x, o);
    if (lane == 0) part[t][wv] = x;
  }
  __syncthreads();
  if (tid < K1_TOK)
    s_buf[tok0 + tid] = part[tid][0] + part[tid][1] + part[tid][2] + part[tid][3];
}

// ---------------- K1.5: per-batch e = exp(s-max), prefix + suffix sums -----
#define ZLD 520
__global__ __launch_bounds__(256) void k15_pre(
    const float* __restrict__ s_buf, float* __restrict__ e_buf,
    float* __restrict__ zpref, float* __restrict__ zsuf)
{
  const int b = blockIdx.x, tid = threadIdx.x;
  __shared__ float se[512];
  __shared__ float bA[512], bB[512];
  __shared__ float pm[4];
  float v0 = s_buf[b * 512 + tid], v1 = s_buf[b * 512 + 256 + tid];
  float m = fmaxf(v0, v1);
  #pragma unroll
  for (int o = 32; o > 0; o >>= 1) m = fmaxf(m, __shfl_xor(m, o));
  if ((tid & 63) == 0) pm[tid >> 6] = m;
  __syncthreads();
  float M = fmaxf(fmaxf(pm[0], pm[1]), fmaxf(pm[2], pm[3]));
  float e0 = expf(v0 - M), e1 = expf(v1 - M);
  se[tid] = e0; se[tid + 256] = e1;
  e_buf[b * 512 + tid] = e0; e_buf[b * 512 + 256 + tid] = e1;
  bA[tid] = e0; bA[tid + 256] = e1;
  __syncthreads();
  float* src = bA; float* dst = bB;
  for (int off = 1; off < 512; off <<= 1) {
    for (int i = tid; i < 512; i += 256)
      dst[i] = src[i] + ((i >= off) ? src[i - off] : 0.f);
    __syncthreads();
    float* t = src; src = dst; dst = t;
  }
  if (tid == 0) zpref[b * ZLD] = 0.f;
  zpref[b * ZLD + 1 + tid] = src[tid];
  zpref[b * ZLD + 257 + tid] = src[tid + 256];
  __syncthreads();
  src[tid] = se[tid]; src[tid + 256] = se[tid + 256];
  __syncthreads();
  for (int off = 1; off < 512; off <<= 1) {
    for (int i = tid; i < 512; i += 256)
      dst[i] = src[i] + ((i + off < 512) ? src[i + off] : 0.f);
    __syncthreads();
    float* t = src; src = dst; dst = t;
  }
  zsuf[b * ZLD + tid] = src[tid];
  zsuf[b * ZLD + 256 + tid] = src[tid + 256];
  if (tid == 0) zsuf[b * ZLD + 512] = 0.f;
}

// ---------------- K2a: per-16-chunk partial sums of e_k * h[k][f] ----------
__global__ __launch_bounds__(256) void k2a_part(
    const float* __restrict__ hidden, const float* __restrict__ e_buf,
    float* __restrict__ spart)
{
  const int bid = blockIdx.x;
  const int fc = bid % 3, c = (bid / 3) % 32, b = bid / 96;
  const int f = fc * 256 + threadIdx.x;
  float acc = 0.f;
  #pragma unroll 4
  for (int kk = 0; kk < 16; ++kk) {
    int k = c * 16 + kk;
    acc += e_buf[b * 512 + k] * hidden[((size_t)(b * 512 + k)) * Hh + f];
  }
  spart[((size_t)b * 32 + c) * Hh + f] = acc;
}

// ---------------- K2c: scan -> hidd (fp32 to d_out, bf16 to ws) ------------
__global__ __launch_bounds__(256) void k2c_scan(
    const float* __restrict__ hidden, const float* __restrict__ e_buf,
    const float* __restrict__ zpref, const float* __restrict__ zsuf,
    const float* __restrict__ spart, const int* __restrict__ ptype,
    float* __restrict__ out_hidd, unsigned short* __restrict__ hbf)
{
  const int bid = blockIdx.x;
  const int fc = bid % 3, q = (bid / 3) % 16, b = bid / 48;
  const int f = fc * 256 + threadIdx.x;
  const int type = ptype[b];
  const float* Sp = spart + (size_t)b * 32 * Hh;
  const float* Zp = zpref + b * ZLD;
  const float* Zs = zsuf + b * ZLD;
  const size_t hbase = (size_t)b * 512 * Hh + f;
  const int j0 = q * 32;
  if (type == 0) {
    float run = 0.f;
    for (int c = 0; c < q * 2; ++c) run += Sp[c * Hh + f];
    for (int jj = 0; jj < 32; ++jj) {
      int j = j0 + jj;
      float ev = e_buf[b * 512 + j];
      float h = hidden[hbase + (size_t)j * Hh];
      run += ev * h;
      float val = run / (Zp[j + 1] * (float)(j + 1));
      out_hidd[hbase + (size_t)j * Hh] = val;
      hbf[hbase + (size_t)j * Hh] = f2bf(val);
    }
  } else if (type == 1) {
    float run = 0.f;
    for (int c = q * 2 + 2; c < 32; ++c) run += Sp[c * Hh + f];
    for (int jj = 31; jj >= 0; --jj) {
      int j = j0 + jj;
      float ev = e_buf[b * 512 + j];
      float h = hidden[hbase + (size_t)j * Hh];
      run += ev * h;
      float val = run / (Zs[j] * (float)(512 - j));
      out_hidd[hbase + (size_t)j * Hh] = val;
      hbf[hbase + (size_t)j * Hh] = f2bf(val);
    }
  } else {
    float T = 0.f;
    for (int c = 0; c < 32; ++c) T += Sp[c * Hh + f];
    float Ztot = Zp[512];
    for (int jj = 0; jj < 32; ++jj) {
      int j = j0 + jj;
      float ev = e_buf[b * 512 + j];
      float h = hidden[hbase + (size_t)j * Hh];
      float val = (T - ev * h) / ((Ztot - ev) * 511.0f);
      out_hidd[hbase + (size_t)j * Hh] = val;
      hbf[hbase + (size_t)j * Hh] = f2bf(val);
    }
  }
}

// ---------------- gemm4 (r11-exact): 128x128 4-wave BK=32, triple buffer ---
// Single barrier per K-step; VGPR=68 (no spill -> counted VMW sound).
// Measured r11: vocab GEMM 143 us, passed twice.
#define CPAD 132
__global__ __launch_bounds__(256, 3) void gemm4(
    const unsigned short* __restrict__ Abf, const unsigned short* __restrict__ Bbf,
    const float* __restrict__ bias, float* __restrict__ C,
    const int M, const int N, const int K, const int ntm)
{
  __shared__ __attribute__((aligned(16))) unsigned char lds[49152];
  const int tid = threadIdx.x;
  const int total = gridDim.x;
  int bid = blockIdx.x;
  if ((total & 7) == 0) bid = (bid & 7) * (total >> 3) + (bid >> 3);  // XCD-chunked
  const int bm = bid % ntm;
  const int bn = bid / ntm;
  const int lane = tid & 63;
  const int wv = tid >> 6;
  const int wr = wv >> 1;
  const int wc = wv & 1;
  const int r15 = lane & 15, kg = lane >> 4;
  const int nt = K / 32;

  unsigned offA[2], offB[2];
  int ldsg[2];
  #pragma unroll
  for (int i = 0; i < 2; ++i) {
    int g = i * 256 + tid;
    int r = ((g >> 6) << 4) | ((g >> 2) & 15);
    int c = (g & 3) ^ ((g >> 4) & 3);
    offA[i] = (unsigned)((bm * 128 + r) * K + c * 8);
    int rb = bn * 128 + r; if (rb >= N) rb = N - 1;
    offB[i] = (unsigned)(rb * K + c * 8);
    ldsg[i] = g * 16;
  }
  const int xq = (kg ^ ((r15 >> 2) & 3)) << 4;

#define STG(t, d) do { \
    unsigned char* lb_ = lds + (d) * 16384; \
    gload16(Abf + offA[0] + (t) * 32, lb_ + ldsg[0]); \
    gload16(Abf + offA[1] + (t) * 32, lb_ + ldsg[1]); \
    gload16(Bbf + offB[0] + (t) * 32, lb_ + 8192 + ldsg[0]); \
    gload16(Bbf + offB[1] + (t) * 32, lb_ + 8192 + ldsg[1]); \
  } while (0)
#define RDALL(d) do { \
    const unsigned char* ab_ = lds + (d) * 16384 + wr * 4096 + r15 * 64 + xq; \
    const unsigned char* bb_ = lds + (d) * 16384 + 8192 + wc * 4096 + r15 * 64 + xq; \
    af[0]  = *reinterpret_cast<const bf16x8*>(ab_); \
    bfr[0] = *reinterpret_cast<const bf16x8*>(bb_); \
    af[1]  = *reinterpret_cast<const bf16x8*>(ab_ + 1024); \
    bfr[1] = *reinterpret_cast<const bf16x8*>(bb_ + 1024); \
    af[2]  = *reinterpret_cast<const bf16x8*>(ab_ + 2048); \
    bfr[2] = *reinterpret_cast<const bf16x8*>(bb_ + 2048); \
    af[3]  = *reinterpret_cast<const bf16x8*>(ab_ + 3072); \
    bfr[3] = *reinterpret_cast<const bf16x8*>(bb_ + 3072); \
  } while (0)

  f32x4 acc[4][4];
  #pragma unroll
  for (int m = 0; m < 4; ++m)
    #pragma unroll
    for (int n = 0; n < 4; ++n)
      #pragma unroll
      for (int r = 0; r < 4; ++r) acc[m][n][r] = 0.f;
  bf16x8 af[4], bfr[4];

  STG(0, 0);
  STG(1, 1);
  VMW(4);
  BAR();

  int c0 = 0, c2 = 2;
  for (int t = 0; t < nt; ++t) {
    RDALL(c0);
    if (t + 2 < nt) STG(t + 2, c2);
    __builtin_amdgcn_s_setprio(1);
    #pragma unroll
    for (int mm = 0; mm < 4; ++mm)
      #pragma unroll
      for (int nn = 0; nn < 4; ++nn)
        acc[mm][nn] = __builtin_amdgcn_mfma_f32_16x16x32_bf16(af[mm], bfr[nn], acc[mm][nn], 0, 0, 0);
    __builtin_amdgcn_s_setprio(0);
    if (t + 2 < nt) { VMW(4); } else { VMW(0); }
    BAR();
    c0 = (c0 == 2) ? 0 : c0 + 1;
    c2 = (c2 == 2) ? 0 : c2 + 1;
  }

  // ---- epilogue: LDS-staged (padded stride), NT full-line stores ----
  float* ldsf = (float*)lds;
  int nvt = N - bn * 128; if (nvt > 128) nvt = 128;
  const int nv = nvt;
  const int colc = (tid & 31) * 4;
  const int rsub = tid >> 5;
  #pragma unroll
  for (int half = 0; half < 2; ++half) {
    BAR();
    if (wr == half) {
      #pragma unroll
      for (int n = 0; n < 4; ++n) {
        int colg = bn * 128 + wc * 64 + n * 16 + r15;
        float bv = (colg < N) ? bias[colg] : 0.f;
        int cloc = wc * 64 + n * 16 + r15;
        #pragma unroll
        for (int m = 0; m < 4; ++m) {
          int rloc = m * 16 + kg * 4;
          #pragma unroll
          for (int rr = 0; rr < 4; ++rr)
            ldsf[(rloc + rr) * CPAD + cloc] = acc[m][n][rr] + bv;
        }
      }
    }
    BAR();
    const int rbase0 = bm * 128 + half * 64;
    if (colc < nv) {
      if (colc + 3 < nv) {
        #pragma unroll
        for (int qq = 0; qq < 8; ++qq) {
          int row = qq * 8 + rsub;
          f32x4 v = *reinterpret_cast<const f32x4*>(&ldsf[row * CPAD + colc]);
          __builtin_nontemporal_store(v,
              reinterpret_cast<f32x4*>(&C[(size_t)(rbase0 + row) * N + bn * 128 + colc]));
        }
      } else {
        for (int qq = 0; qq < 8; ++qq) {
          int row = qq * 8 + rsub;
          f32x4 v = *reinterpret_cast<const f32x4*>(&ldsf[row * CPAD + colc]);
          size_t ga = (size_t)(rbase0 + row) * N + bn * 128 + colc;
          #pragma unroll
          for (int e = 0; e < 4; ++e)
            if (colc + e < nv) C[ga + e] = v[e];
        }
      }
    }
  }
#undef STG
#undef RDALL
}

// ---------------- fallback GEMM (fp32 B, on-the-fly convert) ---------------
#define GBM 128
#define GBN 128
#define GBK 64
__global__ __launch_bounds__(256) void gemm_bt(
    const unsigned short* __restrict__ Abf, const float* __restrict__ Bsrc,
    const float* __restrict__ bias, float* __restrict__ C,
    const int M, const int N, const int K, const int ntm)
{
  __shared__ unsigned short As[GBM * GBK];
  __shared__ unsigned short Bs[GBN * GBK];
  const int tid = threadIdx.x;
  const int total = gridDim.x;
  int bid = blockIdx.x;
  if ((total & 7) == 0) bid = (bid & 7) * (total >> 3) + (bid >> 3);
  const int bm = bid % ntm;
  const int bn = bid / ntm;
  const int lane = tid & 63;
  const int wv = tid >> 6;
  const int wr = wv >> 1, wc = wv & 1;
  const int r15 = lane & 15, kg = lane >> 4;

  f32x4 acc[4][4];
  #pragma unroll
  for (int m = 0; m < 4; ++m)
    #pragma unroll
    for (int n = 0; n < 4; ++n)
      #pragma unroll
      for (int r = 0; r < 4; ++r) acc[m][n][r] = 0.f;

  for (int kt = 0; kt < K; kt += GBK) {
    __syncthreads();
    #pragma unroll
    for (int i = 0; i < 4; ++i) {
      int c = i * 256 + tid;
      int row = c >> 3, col8 = c & 7;
      short8 v = *reinterpret_cast<const short8*>(Abf + (size_t)(bm * GBM + row) * K + kt + col8 * 8);
      int idx = (row * GBK + col8 * 8) ^ ((row & 7) << 3);
      *reinterpret_cast<short8*>(&As[idx]) = v;
    }
    #pragma unroll
    for (int i = 0; i < 8; ++i) {
      int c = i * 256 + tid;
      int row = c >> 4, col4 = c & 15;
      int nsrc = bn * GBN + row; nsrc = nsrc < N ? nsrc : N - 1;
      f32x4 v = *reinterpret_cast<const f32x4*>(Bsrc + (size_t)nsrc * K + kt + col4 * 4);
      short4v p;
      #pragma unroll
      for (int q = 0; q < 4; ++q) p[q] = (short)f2bf(v[q]);
      int idx = (row * GBK + col4 * 4) ^ ((row & 7) << 3);
      *reinterpret_cast<short4v*>(&Bs[idx]) = p;
    }
    __syncthreads();
    #pragma unroll
    for (int kk = 0; kk < GBK / 32; ++kk) {
      bf16x8 af[4], bf[4];
      #pragma unroll
      for (int m = 0; m < 4; ++m) {
        int row = wr * 64 + m * 16 + r15;
        int col = kk * 32 + kg * 8;
        af[m] = *reinterpret_cast<const bf16x8*>(&As[(row * GBK + col) ^ ((row & 7) << 3)]);
      }
      #pragma unroll
      for (int n = 0; n < 4; ++n) {
        int row = wc * 64 + n * 16 + r15;
        int col = kk * 32 + kg * 8;
        bf[n] = *reinterpret_cast<const bf16x8*>(&Bs[(row * GBK + col) ^ ((row & 7) << 3)]);
      }
      #pragma unroll
      for (int m = 0; m < 4; ++m)
        #pragma unroll
        for (int n = 0; n < 4; ++n)
          acc[m][n] = __builtin_amdgcn_mfma_f32_16x16x32_bf16(af[m], bf[n], acc[m][n], 0, 0, 0);
    }
  }
  #pragma unroll
  for (int n = 0; n < 4; ++n) {
    int col = bn * GBN + wc * 64 + n * 16 + r15;
    if (col < N) {
      float bv = bias[col];
      #pragma unroll
      for (int m = 0; m < 4; ++m) {
        int rbase = bm * GBM + wr * 64 + m * 16 + kg * 4;
        #pragma unroll
        for (int r = 0; r < 4; ++r)
          C[(size_t)(rbase + r) * N + col] = acc[m][n][r] + bv;
      }
    }
  }
}

// ---------------- K3b: exact GELU + LayerNorm -> xn (bf16) -----------------
__global__ __launch_bounds__(256) void k3b_geluln(
    const float* __restrict__ x, const float* __restrict__ gam,
    const float* __restrict__ bet, unsigned short* __restrict__ xnbf)
{
  const int row = blockIdx.x, tid = threadIdx.x;
  __shared__ float part[4];
  float g[3];
  float s = 0.f;
  #pragma unroll
  for (int i = 0; i < 3; ++i) {
    float xv = x[(size_t)row * Hh + tid + 256 * i];
    float t = 0.5f * xv * (1.f + erff(xv * 0.70710678118654752f));
    g[i] = t; s += t;
  }
  #pragma unroll
  for (int o = 32; o > 0; o >>= 1) s += __shfl_xor(s, o);
  if ((tid & 63) == 0) part[tid >> 6] = s;
  __syncthreads();
  float mu = (part[0] + part[1] + part[2] + part[3]) * (1.f / 768.f);
  __syncthreads();
  float vs = 0.f;
  #pragma unroll
  for (int i = 0; i < 3; ++i) { float d = g[i] - mu; vs += d * d; }
  #pragma unroll
  for (int o = 32; o > 0; o >>= 1) vs += __shfl_xor(vs, o);
  if ((tid & 63) == 0) part[tid >> 6] = vs;
  __syncthreads();
  float var = (part[0] + part[1] + part[2] + part[3]) * (1.f / 768.f);
  float inv = 1.0f / sqrtf(var + 1e-12f);
  #pragma unroll
  for (int i = 0; i < 3; ++i) {
    int f = tid + 256 * i;
    xnbf[(size_t)row * Hh + f] = f2bf((g[i] - mu) * inv * gam[f] + bet[f]);
  }
}

extern "C" void kernel_launch(void* const* d_in, const int* in_sizes, int n_in,
                              void* d_out, int out_size, void* d_ws, size_t ws_size,
                              hipStream_t stream)
{
  const float* hidden = (const float*)d_in[0];
  const int*   ptype  = (const int*)d_in[1];
  const float* W1     = (const float*)d_in[2];
  const float* b1     = (const float*)d_in[3];
  const float* vat    = (const float*)d_in[4];
  const float* Wfc    = (const float*)d_in[5];
  const float* bfc    = (const float*)d_in[6];
  const float* lng    = (const float*)d_in[7];
  const float* lnb    = (const float*)d_in[8];
  const float* Wout   = (const float*)d_in[9];
  const float* bout   = (const float*)d_in[10];

  float* out_hidd = (float*)d_out;
  float* out_logits = out_hidd + (size_t)Bb * Ss * Hh;

  // workspace layout (float offsets); xnbf reuses hbf (dead after FC GEMM)
  float* ws = (float*)d_ws;
  float* s_buf = ws;                                   // [0, 2048)
  float* e_buf = ws + 2048;                            // [2048, 4096)
  float* zpref = ws + 4096;                            // [4096, 6176)
  float* zsuf  = ws + 6176;                            // [6176, 8256)
  float* xbuf  = ws + 8256;                            // [8256, 1581120)
  float* spart = ws + 1581120;                         // [1581120, 1679424)
  unsigned short* hbf  = (unsigned short*)(ws + 1679424);   // 2048*768 bf16
  unsigned short* xnbf = hbf;                               // reuse (hbf dead)
  unsigned short* wfcb = (unsigned short*)(ws + 2465856);   // 768*768 bf16
  unsigned short* woutb = (unsigned short*)(ws + 2760768);  // 30522*768 bf16
  const size_t need = (size_t)2760768 * 4 + (size_t)Vv * Hh * 2;  // ~57.9 MB

  const bool pre = ws_size >= need;

  k1_score<<<dim3(Bb * Ss / K1_TOK), dim3(256), 0, stream>>>(hidden, W1, b1, vat, s_buf);
  k15_pre<<<dim3(Bb), dim3(256), 0, stream>>>(s_buf, e_buf, zpref, zsuf);
  if (pre) {
    wconv2<<<dim3(2304), dim3(256), 0, stream>>>(Wout, woutb, Wfc, wfcb);
  }
  k2a_part<<<dim3(Bb * 32 * 3), dim3(256), 0, stream>>>(hidden, e_buf, spart);
  k2c_scan<<<dim3(Bb * 16 * 3), dim3(256), 0, stream>>>(hidden, e_buf, zpref, zsuf,
                                                        spart, ptype, out_hidd, hbf);
  if (pre) {
    gemm4<<<dim3((2048 / 128) * (Hh / 128)), dim3(256), 0, stream>>>(
        hbf, wfcb, bfc, xbuf, 2048, Hh, Hh, 2048 / 128);
  } else {
    gemm_bt<<<dim3((2048 / GBM) * (Hh / GBN)), dim3(256), 0, stream>>>(
        hbf, Wfc, bfc, xbuf, 2048, Hh, Hh, 2048 / GBM);
  }
  k3b_geluln<<<dim3(2048), dim3(256), 0, stream>>>(xbuf, lng, lnb, xnbf);
  if (pre) {
    gemm4<<<dim3((2048 / 128) * ((Vv + 127) / 128)), dim3(256), 0, stream>>>(
        xnbf, woutb, bout, out_logits, 2048, Vv, Hh, 2048 / 128);
  } else {
    gemm_bt<<<dim3((2048 / GBM) * ((Vv + GBN - 1) / GBN)), dim3(256), 0, stream>>>(
        xnbf, Wout, bout, out_logits, 2048, Vv, Hh, 2048 / GBM);
  }
}